// Round 3
// baseline (154.607 us; speedup 1.0000x reference)
//
#include <hip/hip_runtime.h>
#include <math.h>

#define EPS 1e-6f

static constexpr int N = 32768;
static constexpr int K = 2048;
static constexpr int D = 768;            // 768 floats = 192 float4 per row
static constexpr int WAVES_PER_BLOCK = 4;
static constexpr int ROWS_PER_WAVE = 4;  // software-pipelined per wave
static constexpr int GRID1 = N / (WAVES_PER_BLOCK * ROWS_PER_WAVE);  // 2048 blocks

// Stage 1: each 64-lane wave handles 4 consecutive rows, double-buffered:
// next row's label + x + gathered-proto loads are issued before the current
// row's FMA/reduce, keeping 12 float4 in flight per wave. One plain store of
// the block partial (no atomics).
__global__ __launch_bounds__(256) void pos_dist_partial_kernel(
        const float* __restrict__ x,
        const float* __restrict__ proto,
        const int*   __restrict__ labels,
        float* __restrict__ partials) {
    const int wave = threadIdx.x >> 6;
    const int lane = threadIdx.x & 63;
    const int gw   = blockIdx.x * WAVES_PER_BLOCK + wave;   // 0..8191
    const int row0 = gw * ROWS_PER_WAVE;

    // Prologue: row 0 of this wave
    int lbl = labels[row0];
    const float4* xr = (const float4*)(x     + (size_t)row0 * D);
    const float4* pr = (const float4*)(proto + (size_t)lbl  * D);
    float4 cx0 = xr[lane], cx1 = xr[64 + lane], cx2 = xr[128 + lane];
    float4 cp0 = pr[lane], cp1 = pr[64 + lane], cp2 = pr[128 + lane];

    float wsum = 0.0f;
    #pragma unroll
    for (int r = 0; r < ROWS_PER_WAVE; ++r) {
        // Prefetch next row before reducing the current one.
        float4 nx0, nx1, nx2, np0, np1, np2;
        if (r + 1 < ROWS_PER_WAVE) {
            const int nrow = row0 + r + 1;
            const int nlbl = labels[nrow];
            const float4* nxr = (const float4*)(x     + (size_t)nrow * D);
            const float4* npr = (const float4*)(proto + (size_t)nlbl * D);
            nx0 = nxr[lane]; nx1 = nxr[64 + lane]; nx2 = nxr[128 + lane];
            np0 = npr[lane]; np1 = npr[64 + lane]; np2 = npr[128 + lane];
        }

        float acc = 0.0f;
        {
            float d;
            d = cx0.x - cp0.x + EPS; acc = fmaf(d, d, acc);
            d = cx0.y - cp0.y + EPS; acc = fmaf(d, d, acc);
            d = cx0.z - cp0.z + EPS; acc = fmaf(d, d, acc);
            d = cx0.w - cp0.w + EPS; acc = fmaf(d, d, acc);
            d = cx1.x - cp1.x + EPS; acc = fmaf(d, d, acc);
            d = cx1.y - cp1.y + EPS; acc = fmaf(d, d, acc);
            d = cx1.z - cp1.z + EPS; acc = fmaf(d, d, acc);
            d = cx1.w - cp1.w + EPS; acc = fmaf(d, d, acc);
            d = cx2.x - cp2.x + EPS; acc = fmaf(d, d, acc);
            d = cx2.y - cp2.y + EPS; acc = fmaf(d, d, acc);
            d = cx2.z - cp2.z + EPS; acc = fmaf(d, d, acc);
            d = cx2.w - cp2.w + EPS; acc = fmaf(d, d, acc);
        }
        #pragma unroll
        for (int off = 32; off > 0; off >>= 1)
            acc += __shfl_down(acc, off, 64);
        if (lane == 0) wsum += sqrtf(acc);

        cx0 = nx0; cx1 = nx1; cx2 = nx2;
        cp0 = np0; cp1 = np1; cp2 = np2;
    }

    __shared__ float red[WAVES_PER_BLOCK];
    if (lane == 0) red[wave] = wsum;
    __syncthreads();
    if (threadIdx.x == 0)
        partials[blockIdx.x] = red[0] + red[1] + red[2] + red[3];
}

// Stage 2: one block reduces GRID1 partials; out = sum / N.
// (The reference's 1/neg_dists.sum() term is exactly 0: each row of
// neg_dists contains an inf, so the sum is inf and its reciprocal is 0.)
__global__ __launch_bounds__(256) void reduce_finalize_kernel(
        const float* __restrict__ partials,
        float* __restrict__ out) {
    const int tid = threadIdx.x;
    const float4* p4 = (const float4*)partials;
    constexpr int NV4 = GRID1 / 4;               // 512 float4

    float acc = 0.0f;
    #pragma unroll
    for (int i = tid; i < NV4; i += 256) {
        float4 v = p4[i];
        acc += v.x + v.y + v.z + v.w;
    }
    #pragma unroll
    for (int off = 32; off > 0; off >>= 1)
        acc += __shfl_down(acc, off, 64);

    __shared__ float red[4];
    const int wave = tid >> 6;
    const int lane = tid & 63;
    if (lane == 0) red[wave] = acc;
    __syncthreads();
    if (tid == 0)
        out[0] = (red[0] + red[1] + red[2] + red[3]) / (float)N;
}

extern "C" void kernel_launch(void* const* d_in, const int* in_sizes, int n_in,
                              void* d_out, int out_size, void* d_ws, size_t ws_size,
                              hipStream_t stream) {
    const float* x      = (const float*)d_in[0];   // [N, D] fp32
    const float* proto  = (const float*)d_in[1];   // [K, D] fp32
    const int*   labels = (const int*)d_in[2];     // [N] int
    float* out      = (float*)d_out;
    float* partials = (float*)d_ws;                // GRID1 floats (8 KB)

    (void)in_sizes; (void)n_in; (void)out_size; (void)ws_size;

    pos_dist_partial_kernel<<<GRID1, 256, 0, stream>>>(x, proto, labels, partials);
    reduce_finalize_kernel<<<1, 256, 0, stream>>>(partials, out);
}

// Round 5
// 149.229 us; speedup vs baseline: 1.0360x; 1.0360x over previous
//
#include <hip/hip_runtime.h>
#include <math.h>

#define EPS 1e-6f

typedef float vfloat4 __attribute__((ext_vector_type(4)));  // native vector:
// __builtin_nontemporal_load requires a native vector type, not HIP_vector_type.

static constexpr int N = 32768;
static constexpr int K = 2048;
static constexpr int D = 768;              // 768 floats = 192 float4 per row
static constexpr int WAVES_PER_BLOCK = 4;
static constexpr int ROWS_PER_WAVE = 4;    // quarter-wave (16 lanes) per row
static constexpr int GRID1 = N / (WAVES_PER_BLOCK * ROWS_PER_WAVE);  // 2048

// Stage 1: quarter-wave row mapping. Each 64-lane wave handles 4 rows
// CONCURRENTLY: lanes [16*s, 16*s+15] own row row0+s, each lane covering 12
// float4 (48 floats) of D=768. All 12 x-loads are issued up front with
// NON-TEMPORAL hints (x is read-once; keep L2 for the 6 MB proto gather set
// that otherwise thrashes the 4 MB per-XCD L2), and they are independent of
// the label->proto dependent chain, which they hide. Per-row reduce is a
// 4-step shuffle within 16 lanes (vs 6-step over 64).
__global__ __launch_bounds__(256) void pos_dist_partial_kernel(
        const float* __restrict__ x,
        const float* __restrict__ proto,
        const int*   __restrict__ labels,
        float* __restrict__ partials) {
    const int wave = threadIdx.x >> 6;
    const int lane = threadIdx.x & 63;
    const int sub  = lane >> 4;            // which of the 4 rows in this wave
    const int sl   = lane & 15;            // lane within the 16-lane row group
    const int row  = (blockIdx.x * WAVES_PER_BLOCK + wave) * ROWS_PER_WAVE + sub;

    const int lbl = labels[row];           // 4 distinct addrs/wave, L1-broadcast

    const vfloat4* __restrict__ xr = (const vfloat4*)(x     + (size_t)row * D);
    const vfloat4* __restrict__ pr = (const vfloat4*)(proto + (size_t)lbl * D);

    // Issue all x loads first (independent of the label-dependent proto chain).
    vfloat4 xv[12];
    #pragma unroll
    for (int j = 0; j < 12; ++j)
        xv[j] = __builtin_nontemporal_load(&xr[sl + 16 * j]);

    float a0 = 0.f, a1 = 0.f, a2 = 0.f, a3 = 0.f;
    #pragma unroll
    for (int j = 0; j < 12; ++j) {
        vfloat4 b = pr[sl + 16 * j];       // normal load: WANT proto cached
        vfloat4 a = xv[j];
        float d0 = a.x - b.x + EPS; a0 = fmaf(d0, d0, a0);
        float d1 = a.y - b.y + EPS; a1 = fmaf(d1, d1, a1);
        float d2 = a.z - b.z + EPS; a2 = fmaf(d2, d2, a2);
        float d3 = a.w - b.w + EPS; a3 = fmaf(d3, d3, a3);
    }
    float acc = (a0 + a1) + (a2 + a3);

    // Reduce across the 16 lanes of this row group.
    #pragma unroll
    for (int off = 8; off > 0; off >>= 1)
        acc += __shfl_down(acc, off, 16);
    float dv = sqrtf(acc);                 // valid on sl==0; harmless elsewhere

    // Sum the 4 row distances of this wave.
    float t = __shfl(dv, 0, 64) + __shfl(dv, 16, 64)
            + __shfl(dv, 32, 64) + __shfl(dv, 48, 64);

    __shared__ float red[WAVES_PER_BLOCK];
    if (lane == 0) red[wave] = t;
    __syncthreads();
    if (threadIdx.x == 0)
        partials[blockIdx.x] = red[0] + red[1] + red[2] + red[3];
}

// Stage 2: one block reduces GRID1 partials; out = sum / N.
// (The reference's 1/neg_dists.sum() term is exactly 0: each row of
// neg_dists contains an inf, so the sum is inf and its reciprocal is 0.)
__global__ __launch_bounds__(256) void reduce_finalize_kernel(
        const float* __restrict__ partials,
        float* __restrict__ out) {
    const int tid = threadIdx.x;
    const vfloat4* p4 = (const vfloat4*)partials;
    constexpr int NV4 = GRID1 / 4;         // 512 float4

    float acc = 0.0f;
    #pragma unroll
    for (int i = tid; i < NV4; i += 256) {
        vfloat4 v = p4[i];
        acc += v.x + v.y + v.z + v.w;
    }
    #pragma unroll
    for (int off = 32; off > 0; off >>= 1)
        acc += __shfl_down(acc, off, 64);

    __shared__ float red[4];
    const int wave = tid >> 6;
    const int lane = tid & 63;
    if (lane == 0) red[wave] = acc;
    __syncthreads();
    if (tid == 0)
        out[0] = (red[0] + red[1] + red[2] + red[3]) / (float)N;
}

extern "C" void kernel_launch(void* const* d_in, const int* in_sizes, int n_in,
                              void* d_out, int out_size, void* d_ws, size_t ws_size,
                              hipStream_t stream) {
    const float* x      = (const float*)d_in[0];   // [N, D] fp32
    const float* proto  = (const float*)d_in[1];   // [K, D] fp32
    const int*   labels = (const int*)d_in[2];     // [N] int
    float* out      = (float*)d_out;
    float* partials = (float*)d_ws;                // GRID1 floats (8 KB)

    (void)in_sizes; (void)n_in; (void)out_size; (void)ws_size;

    pos_dist_partial_kernel<<<GRID1, 256, 0, stream>>>(x, proto, labels, partials);
    reduce_finalize_kernel<<<1, 256, 0, stream>>>(partials, out);
}